// Round 12
// baseline (14.524 us; speedup 1.0000x reference)
//
#include <hip/hip_runtime.h>
#include <math.h>

constexpr int B_DIM = 4096;
constexpr int HO_DIM = 64;
constexpr int NTOT = B_DIM * HO_DIM;      // 262144 matrices per output
constexpr int MPB  = 256;                 // matrices per block (= threads)
constexpr int NBLK = NTOT / MPB;          // 1024 blocks
constexpr float SIGMA_R = 0.05f;
constexpr float SIGMA_T = 0.03f;

typedef float f4 __attribute__((ext_vector_type(4)));
typedef float f2 __attribute__((ext_vector_type(2)));

// Fast exp of se(3) twist (w=[x,y,z], v=[vx,vy,vz]) -> R (row-major 3x3), t.
__device__ __forceinline__ void exp_se3(float x, float y, float z,
                                        float vx, float vy, float vz,
                                        float R[9], float t[3]) {
    float th2 = x*x + y*y + z*z;
    bool small = th2 < 1e-8f;
    float th2s = small ? 1.0f : th2;
    float th = __builtin_amdgcn_sqrtf(th2s);
    float s = __sinf(th);
    float c = __cosf(th);
    float rth  = __builtin_amdgcn_rcpf(th);
    float rth2 = rth * rth;
    float A  = small ? (1.0f - th2 * (1.0f/6.0f))        : (s * rth);
    float Bc = small ? (0.5f - th2 * (1.0f/24.0f))       : ((1.0f - c) * rth2);
    float Cc = small ? (1.0f/6.0f - th2 * (1.0f/120.0f)) : ((th - s) * rth2 * rth);
    R[0] = 1.0f + Bc*(x*x - th2);
    R[1] = -A*z + Bc*x*y;
    R[2] =  A*y + Bc*x*z;
    R[3] =  A*z + Bc*x*y;
    R[4] = 1.0f + Bc*(y*y - th2);
    R[5] = -A*x + Bc*y*z;
    R[6] = -A*y + Bc*x*z;
    R[7] =  A*x + Bc*y*z;
    R[8] = 1.0f + Bc*(z*z - th2);
    float V0 = 1.0f + Cc*(x*x - th2);
    float V1 = -Bc*z + Cc*x*y;
    float V2 =  Bc*y + Cc*x*z;
    float V3 =  Bc*z + Cc*x*y;
    float V4 = 1.0f + Cc*(y*y - th2);
    float V5 = -Bc*x + Cc*y*z;
    float V6 = -Bc*y + Cc*x*z;
    float V7 =  Bc*x + Cc*y*z;
    float V8 = 1.0f + Cc*(z*z - th2);
    t[0] = V0*vx + V1*vy + V2*vz;
    t[1] = V3*vx + V4*vy + V5*vz;
    t[2] = V6*vx + V7*vy + V8*vz;
}

__global__ __launch_bounds__(256) void DiffusionScheduler_kernel(
    const float* __restrict__ twist, const float* __restrict__ noise,
    const float* __restrict__ alpha_bars, const int* __restrict__ timesteps,
    float* __restrict__ out)
{
    // dense input staging: 12 KB, fully-coalesced f4 loads (48 line-
    // transactions/wave vs 144 for strided f2 direct loads)
    __shared__ f4 lds_in[768];                // twist [0,384), noise [384,768)
    // wave-private output transpose (R11 layout: stride-5 f4, conflict-free)
    __shared__ f4 lds_out[4 * 64 * 5];        // 20 KB

    int t  = threadIdx.x;
    int w  = t >> 6;                           // wave id
    int tl = t & 63;                           // lane in wave

    const f4* tw4 = (const f4*)(twist + (size_t)blockIdx.x * 1536);
    const f4* nz4 = (const f4*)(noise + (size_t)blockIdx.x * 1536);
    lds_in[t]       = tw4[t];
    lds_in[384 + t] = nz4[t];
    if (t < 128) {
        lds_in[256 + t]       = tw4[256 + t];
        lds_in[640 + t]       = nz4[256 + t];
    }

    int ts = timesteps[blockIdx.x * 4 + w];    // wave-uniform -> scalar
    float ab = alpha_bars[ts];
    float sab = __builtin_amdgcn_sqrtf(ab);
    float sq  = __builtin_amdgcn_sqrtf(1.0f - ab);
    float kr = sq * SIGMA_R, kt = sq * SIGMA_T;

    __syncthreads();

    // per-thread inputs from LDS (ds_read_b64; 4-way bank alias, negligible)
    const f2* li = (const f2*)lds_in;
    f2 a0 = li[3*t+0], a1 = li[3*t+1], a2 = li[3*t+2];
    f2 n0 = li[768+3*t+0], n1 = li[768+3*t+1], n2 = li[768+3*t+2];

    // ---- phase A: H_noise = exp(sqrt(1-ab) * scale * noise) ----
    float Rn[9], tn[3];
    exp_se3(kr*n0.x, kr*n0.y, kr*n1.x, kt*n1.y, kt*n2.x, kt*n2.y, Rn, tn);

    f4* wl = lds_out + w * 320;                // this wave's region
    wl[tl*5+0] = (f4){Rn[0], Rn[1], Rn[2], tn[0]};
    wl[tl*5+1] = (f4){Rn[3], Rn[4], Rn[5], tn[1]};
    wl[tl*5+2] = (f4){Rn[6], Rn[7], Rn[8], tn[2]};

    __builtin_amdgcn_wave_barrier();           // fence code motion only

    int rr = tl & 3;                           // matrix row this lane stores
    int qq = tl >> 2;
    f4* o0 = ((f4*)out) + (size_t)blockIdx.x * (MPB * 4) + w * 256;
    f4* o1 = o0 + (size_t)NTOT * 4;

    // drain out1 (fire-and-forget; phase B overlaps)
    #pragma unroll
    for (int c = 0; c < 4; ++c) {
        f4 v = (rr == 3) ? (f4){0.0f, 0.0f, 0.0f, 1.0f}
                         : wl[(16*c + qq) * 5 + rr];
        o1[c * 64 + tl] = v;                   // lane-contiguous 1KB/instr
    }

    __builtin_amdgcn_wave_barrier();

    // ---- phase B: H_t = exp(sqrt(ab)*twist); out0 = H_noise @ H_t ----
    // (log(inv(exp(tw))) = -tw; colinear exponentials compose additively)
    float Rt[9], tt[3];
    exp_se3(sab*a0.x, sab*a0.y, sab*a1.x, sab*a1.y, sab*a2.x, sab*a2.y, Rt, tt);

    float R0[9], t0[3];
    #pragma unroll
    for (int r = 0; r < 3; ++r) {
        #pragma unroll
        for (int cdx = 0; cdx < 3; ++cdx) {
            R0[3*r+cdx] = Rn[3*r+0]*Rt[0+cdx] + Rn[3*r+1]*Rt[3+cdx] + Rn[3*r+2]*Rt[6+cdx];
        }
    }
    t0[0] = Rn[0]*tt[0]+Rn[1]*tt[1]+Rn[2]*tt[2] + tn[0];
    t0[1] = Rn[3]*tt[0]+Rn[4]*tt[1]+Rn[5]*tt[2] + tn[1];
    t0[2] = Rn[6]*tt[0]+Rn[7]*tt[1]+Rn[8]*tt[2] + tn[2];

    // re-stage same region (DS ops in-order per wave)
    wl[tl*5+0] = (f4){R0[0], R0[1], R0[2], t0[0]};
    wl[tl*5+1] = (f4){R0[3], R0[4], R0[5], t0[1]};
    wl[tl*5+2] = (f4){R0[6], R0[7], R0[8], t0[2]};

    __builtin_amdgcn_wave_barrier();

    #pragma unroll
    for (int c = 0; c < 4; ++c) {
        f4 v = (rr == 3) ? (f4){0.0f, 0.0f, 0.0f, 1.0f}
                         : wl[(16*c + qq) * 5 + rr];
        o0[c * 64 + tl] = v;                   // lane-contiguous 1KB/instr
    }
}

extern "C" void kernel_launch(void* const* d_in, const int* in_sizes, int n_in,
                              void* d_out, int out_size, void* d_ws, size_t ws_size,
                              hipStream_t stream) {
    const float* twist       = (const float*)d_in[0];
    const float* noise       = (const float*)d_in[1];
    const float* alpha_bars  = (const float*)d_in[2];
    const int*   timesteps   = (const int*)d_in[3];
    float* out = (float*)d_out;

    dim3 block(256);
    dim3 grid(NBLK);
    hipLaunchKernelGGL(DiffusionScheduler_kernel, grid, block, 0, stream,
                       twist, noise, alpha_bars, timesteps, out);
}

// Round 13
// 13.617 us; speedup vs baseline: 1.0666x; 1.0666x over previous
//
#include <hip/hip_runtime.h>
#include <math.h>

constexpr int B_DIM = 4096;
constexpr int HO_DIM = 64;
constexpr int NTOT = B_DIM * HO_DIM;      // 262144 matrices per output
constexpr int MPB  = 256;                 // matrices per block (= threads)
constexpr int NBLK = NTOT / MPB;          // 1024 blocks
constexpr float SIGMA_R = 0.05f;
constexpr float SIGMA_T = 0.03f;

typedef float f4 __attribute__((ext_vector_type(4)));
typedef float f2 __attribute__((ext_vector_type(2)));

// Fast exp of se(3) twist (w=[x,y,z], v=[vx,vy,vz]) -> R (row-major 3x3), t.
__device__ __forceinline__ void exp_se3(float x, float y, float z,
                                        float vx, float vy, float vz,
                                        float R[9], float t[3]) {
    float th2 = x*x + y*y + z*z;
    bool small = th2 < 1e-8f;
    float th2s = small ? 1.0f : th2;
    float th = __builtin_amdgcn_sqrtf(th2s);
    float s = __sinf(th);
    float c = __cosf(th);
    float rth  = __builtin_amdgcn_rcpf(th);
    float rth2 = rth * rth;
    float A  = small ? (1.0f - th2 * (1.0f/6.0f))        : (s * rth);
    float Bc = small ? (0.5f - th2 * (1.0f/24.0f))       : ((1.0f - c) * rth2);
    float Cc = small ? (1.0f/6.0f - th2 * (1.0f/120.0f)) : ((th - s) * rth2 * rth);
    R[0] = 1.0f + Bc*(x*x - th2);
    R[1] = -A*z + Bc*x*y;
    R[2] =  A*y + Bc*x*z;
    R[3] =  A*z + Bc*x*y;
    R[4] = 1.0f + Bc*(y*y - th2);
    R[5] = -A*x + Bc*y*z;
    R[6] = -A*y + Bc*x*z;
    R[7] =  A*x + Bc*y*z;
    R[8] = 1.0f + Bc*(z*z - th2);
    float V0 = 1.0f + Cc*(x*x - th2);
    float V1 = -Bc*z + Cc*x*y;
    float V2 =  Bc*y + Cc*x*z;
    float V3 =  Bc*z + Cc*x*y;
    float V4 = 1.0f + Cc*(y*y - th2);
    float V5 = -Bc*x + Cc*y*z;
    float V6 = -Bc*y + Cc*x*z;
    float V7 =  Bc*x + Cc*y*z;
    float V8 = 1.0f + Cc*(z*z - th2);
    t[0] = V0*vx + V1*vy + V2*vz;
    t[1] = V3*vx + V4*vy + V5*vz;
    t[2] = V6*vx + V7*vy + V8*vz;
}

__global__ __launch_bounds__(256) void DiffusionScheduler_kernel(
    const float* __restrict__ twist, const float* __restrict__ noise,
    const float* __restrict__ alpha_bars, const int* __restrict__ timesteps,
    float* __restrict__ out)
{
    // single [elem][mat] buffer, 12 rows (constant row emitted directly).
    // stride 258 -> all LDS ops <=2-way bank aliasing (free per m136).
    __shared__ float lds[12][258];

    int t = threadIdx.x;
    size_t mat = (size_t)blockIdx.x * MPB + t;

    int ts = timesteps[mat >> 6];              // wave-uniform
    float ab = alpha_bars[ts];
    float sab = __builtin_amdgcn_sqrtf(ab);
    float sq  = __builtin_amdgcn_sqrtf(1.0f - ab);
    float kr = sq * SIGMA_R, kt = sq * SIGMA_T;

    // issue both input loads up front (L3-resident; latency hidden by compute)
    const f2* nz = (const f2*)(noise + 6 * mat);
    f2 n0 = nz[0], n1 = nz[1], n2 = nz[2];
    const f2* tw = (const f2*)(twist + 6 * mat);
    f2 a0 = tw[0], a1 = tw[1], a2 = tw[2];

    // ---- phase A: H_noise = exp(sqrt(1-ab) * scale * noise) ----
    float Rn[9], tn[3];
    exp_se3(kr*n0.x, kr*n0.y, kr*n1.x, kt*n1.y, kt*n2.x, kt*n2.y, Rn, tn);

    lds[ 0][t] = Rn[0]; lds[ 1][t] = Rn[1]; lds[ 2][t] = Rn[2]; lds[ 3][t] = tn[0];
    lds[ 4][t] = Rn[3]; lds[ 5][t] = Rn[4]; lds[ 6][t] = Rn[5]; lds[ 7][t] = tn[1];
    lds[ 8][t] = Rn[6]; lds[ 9][t] = Rn[7]; lds[10][t] = Rn[8]; lds[11][t] = tn[2];

    __syncthreads();

    // drain out1 NOW (stores are fire-and-forget; phase-B VALU hides under them)
    int rr = t & 3;            // matrix row this thread stores
    int mb = t >> 2;           // base matrix within chunk
    f4* o0 = ((f4*)out) + (size_t)blockIdx.x * (MPB * 4);
    f4* o1 = o0 + (size_t)NTOT * 4;

    #pragma unroll
    for (int c = 0; c < 4; ++c) {
        int m = c * 64 + mb;
        f4 v = (rr == 3) ? (f4){0.0f, 0.0f, 0.0f, 1.0f}
                         : (f4){lds[4*rr+0][m], lds[4*rr+1][m], lds[4*rr+2][m], lds[4*rr+3][m]};
        o1[c * 256 + t] = v;                   // lane-contiguous dwordx4
    }

    // ---- phase B (overlaps out1 store drain): H_t and the product ----
    // H_t = exp(sqrt(ab)*twist)
    // (log(inv(exp(tw))) = -tw; colinear exponentials compose additively)
    float Rt[9], tt[3];
    exp_se3(sab*a0.x, sab*a0.y, sab*a1.x, sab*a1.y, sab*a2.x, sab*a2.y, Rt, tt);

    float R0[9], t0[3];
    #pragma unroll
    for (int r = 0; r < 3; ++r) {
        #pragma unroll
        for (int cdx = 0; cdx < 3; ++cdx) {
            R0[3*r+cdx] = Rn[3*r+0]*Rt[0+cdx] + Rn[3*r+1]*Rt[3+cdx] + Rn[3*r+2]*Rt[6+cdx];
        }
    }
    t0[0] = Rn[0]*tt[0]+Rn[1]*tt[1]+Rn[2]*tt[2] + tn[0];
    t0[1] = Rn[3]*tt[0]+Rn[4]*tt[1]+Rn[5]*tt[2] + tn[1];
    t0[2] = Rn[6]*tt[0]+Rn[7]*tt[1]+Rn[8]*tt[2] + tn[2];

    __syncthreads();                           // WAR: all lds reads above done

    lds[ 0][t] = R0[0]; lds[ 1][t] = R0[1]; lds[ 2][t] = R0[2]; lds[ 3][t] = t0[0];
    lds[ 4][t] = R0[3]; lds[ 5][t] = R0[4]; lds[ 6][t] = R0[5]; lds[ 7][t] = t0[1];
    lds[ 8][t] = R0[6]; lds[ 9][t] = R0[7]; lds[10][t] = R0[8]; lds[11][t] = t0[2];

    __syncthreads();

    #pragma unroll
    for (int c = 0; c < 4; ++c) {
        int m = c * 64 + mb;
        f4 v = (rr == 3) ? (f4){0.0f, 0.0f, 0.0f, 1.0f}
                         : (f4){lds[4*rr+0][m], lds[4*rr+1][m], lds[4*rr+2][m], lds[4*rr+3][m]};
        o0[c * 256 + t] = v;                   // lane-contiguous dwordx4
    }
}

extern "C" void kernel_launch(void* const* d_in, const int* in_sizes, int n_in,
                              void* d_out, int out_size, void* d_ws, size_t ws_size,
                              hipStream_t stream) {
    const float* twist       = (const float*)d_in[0];
    const float* noise       = (const float*)d_in[1];
    const float* alpha_bars  = (const float*)d_in[2];
    const int*   timesteps   = (const int*)d_in[3];
    float* out = (float*)d_out;

    dim3 block(256);
    dim3 grid(NBLK);
    hipLaunchKernelGGL(DiffusionScheduler_kernel, grid, block, 0, stream,
                       twist, noise, alpha_bars, timesteps, out);
}